// Round 2
// baseline (869.818 us; speedup 1.0000x reference)
//
#include <hip/hip_runtime.h>

#define PLANE (512 * 512)
#define NB 8
#define CI 64
#define CO 64
#define TP 256  // pixels per tile

// ---------------------------------------------------------------------------
// Kernel 1: compute modulated+demodulated weights into d_ws.
// wt[n][ci][co]  (ci-major so that for a fixed ci, co values are contiguous)
// ---------------------------------------------------------------------------
__global__ void modprep_kernel(const float* __restrict__ style,
                               const float* __restrict__ weight,
                               const float* __restrict__ w_mod,
                               const float* __restrict__ b_mod,
                               float* __restrict__ wt_ws) {
  const int n = blockIdx.x;     // batch
  const int tid = threadIdx.x;  // 0..255
  __shared__ float s_lds[CI];

  // s[ci] = b_mod[ci] + dot(style[n,:], w_mod[ci,:])   (512-dot, 4 threads/ci)
  const int ci = tid >> 2;
  const int part = tid & 3;
  const float4* st4 = (const float4*)(style + n * 512 + part * 128);
  const float4* wm4 = (const float4*)(w_mod + ci * 512 + part * 128);
  float acc = 0.f;
#pragma unroll
  for (int k = 0; k < 32; ++k) {
    float4 a = st4[k], b = wm4[k];
    acc += a.x * b.x + a.y * b.y + a.z * b.z + a.w * b.w;
  }
  acc += __shfl_xor(acc, 1);
  acc += __shfl_xor(acc, 2);
  if (part == 0) s_lds[ci] = acc + b_mod[ci];
  __syncthreads();

  // demodulate per co, write wt[n][c][co]
  if (tid < CO) {
    const int co = tid;
    float sum = 0.f;
#pragma unroll
    for (int c = 0; c < CI; ++c) {
      float w = weight[co * CI + c] * s_lds[c];
      sum += w * w;
    }
    const float demod = rsqrtf(sum + 1e-8f);
#pragma unroll
    for (int c = 0; c < CI; ++c) {
      wt_ws[n * (CI * CO) + c * CO + co] = weight[co * CI + c] * s_lds[c] * demod;
    }
  }
}

// ---------------------------------------------------------------------------
// Kernel 2: per-batch 1x1 channel-mix GEMM over pixels.
// Block: one (n, 256-pixel tile). 256 threads = 4 waves.
//   wave g (=tid>>6) owns co in [16g, 16g+16); lane owns 4 contiguous pixels.
//   x tile staged in LDS via global_load_lds width=16 (1 instr per ci row).
// ---------------------------------------------------------------------------
__global__ __launch_bounds__(256, 2) void modconv_kernel(
    const float* __restrict__ x, const float* __restrict__ wt_ws,
    float* __restrict__ out) {
  __shared__ float xs[CI][TP];    // 64 KB
  __shared__ float wts[CI * CO];  // 16 KB, wts[ci*64 + co]

  const int bid = blockIdx.x;
  const int n = bid >> 10;  // 1024 tiles per batch
  const int pix0 = (bid & 1023) * TP;
  const int tid = threadIdx.x;
  const int wid = tid >> 6;
  const int lane = tid & 63;

  // wt tile -> LDS (16 KB, coalesced, hits L2/L3)
  const float* wsrc = wt_ws + n * (CI * CO);
#pragma unroll
  for (int i = 0; i < 16; ++i) wts[tid + i * 256] = wsrc[tid + i * 256];

  // x tile -> LDS: each wave stages 16 ci-rows; one global_load_lds per row
  // (64 lanes x 16 B = 1024 B = one full 256-float row, linear dest)
  const float* xbase = x + (size_t)n * CI * PLANE + pix0;
#pragma unroll
  for (int r = 0; r < 16; ++r) {
    const int ci = wid * 16 + r;
    const float* gsrc = xbase + (size_t)ci * PLANE + lane * 4;
    __builtin_amdgcn_global_load_lds(
        (__attribute__((address_space(1))) void*)gsrc,
        (__attribute__((address_space(3))) void*)(&xs[ci][0]), 16, 0, 0);
  }
  __syncthreads();  // drains lgkmcnt (wts) + vmcnt (global_load_lds)

  const int g = wid;           // co group: co = 16*g + cc
  const int p = lane * 4;      // pixel offset within tile
  float acc[16][4];
#pragma unroll
  for (int cc = 0; cc < 16; ++cc)
#pragma unroll
    for (int j = 0; j < 4; ++j) acc[cc][j] = 0.f;

#pragma unroll 8
  for (int ci = 0; ci < CI; ++ci) {
    const float4 xv = *(const float4*)&xs[ci][p];  // contiguous b128, conflict-free
    const float xvv[4] = {xv.x, xv.y, xv.z, xv.w};
    const float* wrow = &wts[ci * CO + g * 16];
#pragma unroll
    for (int c4 = 0; c4 < 4; ++c4) {
      const float4 w4 = *(const float4*)&wrow[c4 * 4];  // wave-broadcast b128
      const float wv[4] = {w4.x, w4.y, w4.z, w4.w};
#pragma unroll
      for (int k = 0; k < 4; ++k)
#pragma unroll
        for (int j = 0; j < 4; ++j) acc[c4 * 4 + k][j] += wv[k] * xvv[j];
    }
  }

  // store: 16 co rows x 4 pixels, float4 per row, coalesced
  float* obase = out + ((size_t)(n * CO + g * 16)) * PLANE + pix0 + p;
#pragma unroll
  for (int cc = 0; cc < 16; ++cc) {
    float4 v = make_float4(acc[cc][0], acc[cc][1], acc[cc][2], acc[cc][3]);
    *(float4*)(obase + (size_t)cc * PLANE) = v;
  }
}

// ---------------------------------------------------------------------------
extern "C" void kernel_launch(void* const* d_in, const int* in_sizes, int n_in,
                              void* d_out, int out_size, void* d_ws,
                              size_t ws_size, hipStream_t stream) {
  const float* x = (const float*)d_in[0];       // (8, 64, 512, 512)
  const float* style = (const float*)d_in[1];   // (8, 512)
  const float* weight = (const float*)d_in[2];  // (1, 64, 64, 1, 1)
  const float* w_mod = (const float*)d_in[3];   // (64, 512)
  const float* b_mod = (const float*)d_in[4];   // (64,)
  float* out = (float*)d_out;                   // (8, 64, 512, 512)
  float* wt_ws = (float*)d_ws;                  // 8*64*64 floats = 128 KB

  modprep_kernel<<<NB, 256, 0, stream>>>(style, weight, w_mod, b_mod, wt_ws);
  modconv_kernel<<<NB * 1024, 256, 0, stream>>>(x, wt_ws, out);
}